// Round 4
// baseline (950.367 us; speedup 1.0000x reference)
//
#include <hip/hip_runtime.h>

// Problem: T=128, B=256, D_G=512, D_H=1024
//   zg = z @ W_g^T + b_h   (one big GEMM, precomputed)
//   h_t = relu(LN(h_{t-1} @ W_h^T + zg_t)), h_0 = 0; out = all h_t (fp32)
//
// Persistent RNN kernel: 256 blocks x 256 threads (1 block/CU).
//   16 row-groups (16 batch rows) x 16 column-members (64 cols each).
//   W_h slice pinned in VGPR/AGPRs. ONE group barrier per step; cross-block
//   traffic via relaxed agent-scope atomics (cache-bypass, L3-coherent).
// R4 hardening vs R3 (replay-only failures = publish/flag reorder race):
//   - explicit `s_waitcnt vmcnt(0)` + memory clobber in EVERY thread after
//     the publish stores (compiler may sink relaxed agent stores past the
//     workgroup-scope fence in __syncthreads and past the relaxed flag add)
//   - gather reads all 16 chunks from global (dropped LDS shortcut)

#define T_STEPS 128
#define B_SZ    256
#define DG      512
#define DH      1024

typedef short s16x8 __attribute__((ext_vector_type(8)));   // 8 bf16
typedef short s16x4 __attribute__((ext_vector_type(4)));
typedef float f32x4 __attribute__((ext_vector_type(4)));
typedef unsigned long long u64;

__device__ inline short f2bf(float f) {
  unsigned u = __builtin_bit_cast(unsigned, f);
  unsigned r = (u + 0x7fffu + ((u >> 16) & 1u)) >> 16;   // RNE
  return (short)r;
}
__device__ inline float bf2f(short h) {
  unsigned u = ((unsigned)(unsigned short)h) << 16;
  return __builtin_bit_cast(float, u);
}
__device__ inline s16x8 pk8(f32x4 a, f32x4 b) {
  s16x8 r;
  r[0] = f2bf(a[0]); r[1] = f2bf(a[1]); r[2] = f2bf(a[2]); r[3] = f2bf(a[3]);
  r[4] = f2bf(b[0]); r[5] = f2bf(b[1]); r[6] = f2bf(b[2]); r[7] = f2bf(b[3]);
  return r;
}
__device__ inline f32x4 mfma16x32(s16x8 a, s16x8 b, f32x4 c) {
  return __builtin_amdgcn_mfma_f32_16x16x32_bf16(a, b, c, 0, 0, 0);
}
__device__ inline float rsum16(float v) {
  v += __shfl_xor(v, 1);
  v += __shfl_xor(v, 2);
  v += __shfl_xor(v, 4);
  v += __shfl_xor(v, 8);
  return v;
}
#define ATOM_ST(p, v) __hip_atomic_store((p), (v), __ATOMIC_RELAXED, __HIP_MEMORY_SCOPE_AGENT)
#define ATOM_LD(p)    __hip_atomic_load((p), __ATOMIC_RELAXED, __HIP_MEMORY_SCOPE_AGENT)

// ---------------------------------------------------------------------------
// prep: W_h fragments in MFMA B-operand lane layout (bf16); zero barriers.
// frag layout: [memblk 16][wave 4][kstep 32][lane 64][j 8]
//   value = W_h[memblk*64 + wave*16 + (lane&15)][kstep*32 + (lane>>4)*8 + j]
// ---------------------------------------------------------------------------
__global__ __launch_bounds__(256) void prep_kernel(
    const float* __restrict__ Wh, short* __restrict__ frag_w,
    int* __restrict__ bars) {
  int i = blockIdx.x * 256 + threadIdx.x;              // grid 4096 -> 1,048,576
  int j    = i & 7;
  int lane = (i >> 3) & 63;
  int ks   = (i >> 9) & 31;
  int w    = (i >> 14) & 3;
  int b    = i >> 16;
  int row = b * 64 + w * 16 + (lane & 15);
  int col = ks * 32 + (lane >> 4) * 8 + j;
  frag_w[i] = f2bf(Wh[row * DH + col]);
  if (i < 512) bars[i] = 0;
}

// ---------------------------------------------------------------------------
// zg GEMM: zg[t*B+b][n] = sum_k z[t*B+b][k]*W_g[n][k] + b_h[n]  (bf16 out)
// ---------------------------------------------------------------------------
__global__ __launch_bounds__(256) void zg_gemm(
    const float* __restrict__ Z, const float* __restrict__ Wg,
    const float* __restrict__ bh, short* __restrict__ zg) {
  const int tid  = threadIdx.x;
  const int m0   = blockIdx.x * 128;
  const int n0   = blockIdx.y * 128;
  const int w    = tid >> 6, lane = tid & 63, ln = lane & 15, quad = lane >> 4;
  const int wm   = w & 1, wn = w >> 1;
  const int srow = tid >> 1, shalf = tid & 1;

  __shared__ short As[128 * 40];
  __shared__ short Bs[128 * 40];
  f32x4 acc[4][4] = {};

  for (int k0 = 0; k0 < DG; k0 += 32) {
    __syncthreads();
    {
      const float* sA = Z + (m0 + srow) * DG + k0 + shalf * 16;
      f32x4 a0 = *(const f32x4*)sA,       a1 = *(const f32x4*)(sA + 4);
      f32x4 a2 = *(const f32x4*)(sA + 8), a3 = *(const f32x4*)(sA + 12);
      s16x8* dA = (s16x8*)&As[srow * 40 + shalf * 16];
      dA[0] = pk8(a0, a1); dA[1] = pk8(a2, a3);
      const float* sB = Wg + (n0 + srow) * DG + k0 + shalf * 16;
      f32x4 b0 = *(const f32x4*)sB,       b1 = *(const f32x4*)(sB + 4);
      f32x4 b2 = *(const f32x4*)(sB + 8), b3 = *(const f32x4*)(sB + 12);
      s16x8* dB = (s16x8*)&Bs[srow * 40 + shalf * 16];
      dB[0] = pk8(b0, b1); dB[1] = pk8(b2, b3);
    }
    __syncthreads();
    s16x8 af[4], bf[4];
#pragma unroll
    for (int i = 0; i < 4; i++) {
      af[i] = *(const s16x8*)&As[(wm * 64 + i * 16 + ln) * 40 + quad * 8];
      bf[i] = *(const s16x8*)&Bs[(wn * 64 + i * 16 + ln) * 40 + quad * 8];
    }
#pragma unroll
    for (int mi = 0; mi < 4; mi++)
#pragma unroll
      for (int ni = 0; ni < 4; ni++)
        acc[mi][ni] = mfma16x32(af[mi], bf[ni], acc[mi][ni]);
  }
#pragma unroll
  for (int ni = 0; ni < 4; ni++) {
    int col = n0 + wn * 64 + ni * 16 + ln;
    float bhv = bh[col];
#pragma unroll
    for (int mi = 0; mi < 4; mi++) {
      int row = m0 + wm * 64 + mi * 16 + quad * 4;
#pragma unroll
      for (int r = 0; r < 4; r++)
        zg[(row + r) * DH + col] = f2bf(acc[mi][ni][r] + bhv);
    }
  }
}

// ---------------------------------------------------------------------------
// persistent RNN. group g = bid>>4 owns rows [16g,16g+16); member = bid&15
// owns cols [64m,64m+64); wave w owns 16 cols of those.
// ---------------------------------------------------------------------------
__global__ __launch_bounds__(256, 1) void rnn_kernel(
    const short* __restrict__ zg, const short* __restrict__ frag_w,
    u64* __restrict__ preU,                 // [2][256][256] u64 (bf16 x4)
    u64* __restrict__ stats,                // [2][16][16 mem][16 row]
    int* __restrict__ bars, const float* __restrict__ gamma,
    const float* __restrict__ beta, float* __restrict__ out) {
  const int tid = threadIdx.x, bid = blockIdx.x;
  const int g = bid >> 4, mem = bid & 15;
  const int w = tid >> 6, lane = tid & 63, ln = lane & 15, quad = lane >> 4;
  const int colw = mem * 64 + w * 16 + ln;     // GEMM output column
  const int rowBase = g * 16;
  const int sr = tid >> 4, sj = tid & 15;      // stage/publish role

  __shared__ short Alds[16 * 1032];            // h state, 16 x 1024 (+8 pad)
  __shared__ short Plds[16 * 68];              // own pre tile, 16 x 64 (+4 pad)
  __shared__ float sSum[4][16], sSq[4][16];    // per-wave LN partials
  __shared__ float sS[16][16], sQ[16][16];     // gathered member stats
  __shared__ float gbe[2][1024];               // gamma, beta

  for (int i = tid; i < 1024; i += 256) { gbe[0][i] = gamma[i]; gbe[1][i] = beta[i]; }
  {
    s16x8 z8 = {};
    for (int c = tid; c < 2064; c += 256) ((s16x8*)Alds)[c] = z8;
  }
  // W_h B-fragments resident in VGPR/AGPRs (128 regs)
  s16x8 Wf[32];
  {
    const s16x8* fw = (const s16x8*)frag_w + (size_t)(mem * 4 + w) * 32 * 64;
#pragma unroll
    for (int ks = 0; ks < 32; ks++) Wf[ks] = fw[ks * 64 + lane];
  }
  int* gbar = &bars[g * 32];
  __syncthreads();

#pragma unroll 1
  for (int t = 0; t < T_STEPS; t++) {
    const int p = t & 1;
#pragma unroll
    for (int i2 = 0; i2 < 32; i2++) asm volatile("" : "+v"(Wf[i2]));

    // ---- zg loads hoisted above GEMM (latency hides under MFMA)
    short zv[4];
    {
      int zbase = (t * B_SZ + rowBase + quad * 4) * DH + colw;
#pragma unroll
      for (int r = 0; r < 4; r++) zv[r] = zg[zbase + r * DH];
    }

    // ---- GEMM on h_{t-1} (in LDS): 16 rows x 16 cols per wave, K=1024
    f32x4 acc0 = {0.f, 0.f, 0.f, 0.f}, acc1 = {0.f, 0.f, 0.f, 0.f};
#pragma unroll
    for (int ks = 0; ks < 32; ks += 2) {
      s16x8 a0 = *(const s16x8*)&Alds[ln * 1032 + ks * 32 + quad * 8];
      s16x8 a1 = *(const s16x8*)&Alds[ln * 1032 + ks * 32 + 32 + quad * 8];
      acc0 = mfma16x32(a0, Wf[ks], acc0);
      acc1 = mfma16x32(a1, Wf[ks + 1], acc1);
    }
    // pre = acc + zg; write into Plds tile + per-wave LN partials
    float pre[4];
#pragma unroll
    for (int r = 0; r < 4; r++) pre[r] = acc0[r] + acc1[r] + bf2f(zv[r]);
#pragma unroll
    for (int r = 0; r < 4; r++) {
      Plds[(quad * 4 + r) * 68 + w * 16 + ln] = f2bf(pre[r]);
      float s = rsum16(pre[r]);
      float q = rsum16(pre[r] * pre[r]);
      if (ln == 0) { sSum[w][quad * 4 + r] = s; sSq[w][quad * 4 + r] = q; }
    }
    __syncthreads();
    // ---- coalesced publish: 256 threads x 8 B = full 16x64 bf16 tile
    ATOM_ST(&preU[(p * B_SZ + rowBase + sr) * 256 + mem * 16 + sj],
            *(const u64*)&Plds[sr * 68 + sj * 4]);
    if (tid < 16) {
      float s = sSum[0][tid] + sSum[1][tid] + sSum[2][tid] + sSum[3][tid];
      float q = sSq[0][tid] + sSq[1][tid] + sSq[2][tid] + sSq[3][tid];
      float2 f2; f2.x = s; f2.y = q;
      ATOM_ST(&stats[((p * 16 + g) * 16 + mem) * 16 + tid],
              __builtin_bit_cast(u64, f2));
    }
    // HARDEN: every wave drains its publish stores to the coherence point
    // BEFORE arriving at the barrier; clobber pins compiler ordering.
    asm volatile("s_waitcnt vmcnt(0)" ::: "memory");
    // ---- ONE group barrier
    __syncthreads();
    if (tid == 0) {
      __hip_atomic_fetch_add(gbar, 1, __ATOMIC_RELAXED, __HIP_MEMORY_SCOPE_AGENT);
      int target = (t + 1) * 16;
      while (__hip_atomic_load(gbar, __ATOMIC_RELAXED, __HIP_MEMORY_SCOPE_AGENT) < target)
        __builtin_amdgcn_s_sleep(1);
    }
    __syncthreads();
    asm volatile("" ::: "memory");         // no gather load hoists above spin

    // ---- stage: gather pre_t + stats
    u64 pr[16];
    {
      int rbase = (p * B_SZ + rowBase + sr) * 256;
#pragma unroll
      for (int k = 0; k < 16; k++)
        pr[k] = ATOM_LD(&preU[rbase + k * 16 + sj]);
    }
    {
      int m2 = tid >> 4, row = tid & 15;
      float2 f2 = __builtin_bit_cast(float2,
          ATOM_LD(&stats[((p * 16 + g) * 16 + m2) * 16 + row]));
      sS[m2][row] = f2.x; sQ[m2][row] = f2.y;
    }
    __syncthreads();
    float mean, rstd;
    {
      float s = 0.f, q = 0.f;
#pragma unroll
      for (int m2 = 0; m2 < 16; m2++) { s += sS[m2][sr]; q += sQ[m2][sr]; }
      mean = s * (1.0f / 1024.0f);
      float var = q * (1.0f / 1024.0f) - mean * mean;
      rstd = __frsqrt_rn(var + 1e-5f);
    }
    {
      float* orow = out + (size_t)(t * B_SZ + rowBase + sr) * DH;
      short* lrow = &Alds[sr * 1032];
#pragma unroll
      for (int k = 0; k < 16; k++) {
        int c = k * 64 + sj * 4;
        s16x4 pv = __builtin_bit_cast(s16x4, pr[k]);
        f32x4 hv; s16x4 hb;
#pragma unroll
        for (int i = 0; i < 4; i++) {
          float x = (bf2f(pv[i]) - mean) * rstd * gbe[0][c + i] + gbe[1][c + i];
          x = fmaxf(x, 0.0f);
          hv[i] = x; hb[i] = f2bf(x);
        }
        *(f32x4*)&orow[c] = hv;
        *(s16x4*)&lrow[c] = hb;
      }
    }
    __syncthreads();                       // h_t in LDS ready for next GEMM
  }
}

// ---------------------------------------------------------------------------
extern "C" void kernel_launch(void* const* d_in, const int* in_sizes, int n_in,
                              void* d_out, int out_size, void* d_ws, size_t ws_size,
                              hipStream_t stream) {
  const float* Z   = (const float*)d_in[0];   // [128,256,512]
  const float* Wh  = (const float*)d_in[1];   // [1024,1024]
  const float* Wg  = (const float*)d_in[2];   // [1024,512]
  const float* bh  = (const float*)d_in[3];   // [1024]
  const float* gam = (const float*)d_in[4];   // [1024]
  const float* bet = (const float*)d_in[5];   // [1024]
  float* out = (float*)d_out;                 // [128,256,1024] fp32

  char* ws = (char*)d_ws;
  short* zg      = (short*)(ws);               // 64 MiB
  short* frag_w  = (short*)(ws + 67108864);    // 2 MiB
  u64*   preU    = (u64*)  (ws + 69206016);    // [2][256][256] u64 = 1 MiB
  u64*   stats   = (u64*)  (ws + 70254592);    // [2][16][16][16] u64 = 64 KiB
  int*   bars    = (int*)  (ws + 70320128);    // 512 ints

  prep_kernel<<<4096, 256, 0, stream>>>(Wh, frag_w, bars);
  zg_gemm<<<dim3(256, 8), 256, 0, stream>>>(Z, Wg, bh, zg);
  rnn_kernel<<<256, 256, 0, stream>>>(zg, frag_w, preU, stats, bars, gam, bet, out);
}